// Round 3
// baseline (138.084 us; speedup 1.0000x reference)
//
#include <hip/hip_runtime.h>

// Problem constants (match reference file)
#define NROWS    256
#define DCOLS    65536
#define MAXLEN   8192
#define BLKROW   8                    // kernel-1 blocks per row
#define K1TPB    256
#define K1V4     8                    // float4 per thread: 8*4*256 = 8192 elems/block
#define K2TPB    1024
#define K2V4     16                   // slow path: 16 float4/thread
#define NWAVE2   (K2TPB / 64)

// Semantics: y[i,j] = x[i,j] if x[i,j]!=0 and rank of j among row i's
// nonzeros < MAXLEN, else 0.  When row_nnz <= MAXLEN this is exactly y = x.

// ---- Kernel 1: streaming y=x copy + per-block nonzero count ----
__global__ __launch_bounds__(K1TPB) void copy_count_kernel(
        const float* __restrict__ x, float* __restrict__ y,
        int* __restrict__ blk_cnt) {
    const int t    = threadIdx.x;
    const int lane = t & 63;
    const int wave = t >> 6;
    const size_t base4 = (size_t)blockIdx.x * (K1TPB * K1V4);  // float4 index

    const float4* __restrict__ x4 = reinterpret_cast<const float4*>(x) + base4;
    float4* __restrict__ y4       = reinterpret_cast<float4*>(y) + base4;

    int cnt = 0;
#pragma unroll
    for (int i = 0; i < K1V4; ++i) {
        float4 v = x4[i * K1TPB + t];
        cnt += (v.x != 0.0f) + (v.y != 0.0f) + (v.z != 0.0f) + (v.w != 0.0f);
        y4[i * K1TPB + t] = v;
    }

    // wave butterfly reduce
#pragma unroll
    for (int off = 32; off; off >>= 1) cnt += __shfl_xor(cnt, off, 64);

    __shared__ int wsum[K1TPB / 64];
    if (lane == 0) wsum[wave] = cnt;
    __syncthreads();
    if (t == 0) {
        int acc = 0;
#pragma unroll
        for (int w = 0; w < K1TPB / 64; ++w) acc += wsum[w];
        blk_cnt[blockIdx.x] = acc;
    }
}

// ---- Kernel 2: per-row check; slow-path rank cutoff only if nnz > MAXLEN ----
__global__ __launch_bounds__(K2TPB) void fixup_kernel(
        const float* __restrict__ x, float* __restrict__ y,
        const int* __restrict__ blk_cnt) {
    const int row  = blockIdx.x;
    const int t    = threadIdx.x;
    const int lane = t & 63;
    const int wave = t >> 6;

    __shared__ int csh[BLKROW];
    if (t < BLKROW) csh[t] = blk_cnt[row * BLKROW + t];
    __syncthreads();
    int nnz = 0;
#pragma unroll
    for (int b = 0; b < BLKROW; ++b) nnz += csh[b];   // block-uniform

    if (nnz <= MAXLEN) return;   // y == x already written by kernel 1

    // Slow path (never taken for this data; kept for general correctness).
    // Ordered rank cutoff over contiguous per-thread chunks; row is L3-hot.
    const float4* __restrict__ xc =
        reinterpret_cast<const float4*>(x + (size_t)row * DCOLS) + t * K2V4;
    float4* __restrict__ yc =
        reinterpret_cast<float4*>(y + (size_t)row * DCOLS) + t * K2V4;

    int ccnt = 0;
#pragma unroll
    for (int i = 0; i < K2V4; ++i) {
        float4 w = xc[i];
        ccnt += (w.x != 0.0f) + (w.y != 0.0f) + (w.z != 0.0f) + (w.w != 0.0f);
    }
    // wave inclusive scan
    int incl = ccnt;
#pragma unroll
    for (int off = 1; off < 64; off <<= 1) {
        int n = __shfl_up(incl, off, 64);
        if (lane >= off) incl += n;
    }
    __shared__ int wsum[NWAVE2];
    __shared__ int wbase[NWAVE2];
    if (lane == 63) wsum[wave] = incl;
    __syncthreads();
    if (t == 0) {
        int acc = 0;
#pragma unroll
        for (int w = 0; w < NWAVE2; ++w) { wbase[w] = acc; acc += wsum[w]; }
    }
    __syncthreads();
    int rank = wbase[wave] + (incl - ccnt);

#pragma unroll
    for (int i = 0; i < K2V4; ++i) {
        float4 w = xc[i];
        float4 o;
        bool nx = (w.x != 0.0f); o.x = (nx && rank < MAXLEN) ? w.x : 0.0f; rank += nx;
        bool ny = (w.y != 0.0f); o.y = (ny && rank < MAXLEN) ? w.y : 0.0f; rank += ny;
        bool nz = (w.z != 0.0f); o.z = (nz && rank < MAXLEN) ? w.z : 0.0f; rank += nz;
        bool nw = (w.w != 0.0f); o.w = (nw && rank < MAXLEN) ? w.w : 0.0f; rank += nw;
        yc[i] = o;
    }
}

extern "C" void kernel_launch(void* const* d_in, const int* in_sizes, int n_in,
                              void* d_out, int out_size, void* d_ws, size_t ws_size,
                              hipStream_t stream) {
    // d_in[0] = t (unused), d_in[1] = x (256*65536 f32), d_in[2] = embed_table (unused).
    const float* x = (const float*)d_in[1];
    float* y = (float*)d_out;
    int* blk_cnt = (int*)d_ws;   // NROWS*BLKROW = 2048 ints

    copy_count_kernel<<<NROWS * BLKROW, K1TPB, 0, stream>>>(x, y, blk_cnt);
    fixup_kernel<<<NROWS, K2TPB, 0, stream>>>(x, y, blk_cnt);
}